// Round 1
// baseline (396.884 us; speedup 1.0000x reference)
//
#include <hip/hip_runtime.h>
#include <hip/hip_bf16.h>

#define B_ 8
#define C_ 128
#define N_ 4096   // H*W = 64*64

typedef __bf16 bf16x8 __attribute__((ext_vector_type(8)));
typedef float  f32x4  __attribute__((ext_vector_type(4)));
typedef unsigned short u16x8 __attribute__((ext_vector_type(8)));

// ---------------------------------------------------------------------------
// Kernel A: channel softmax over C for each (b, n).
//   writes xs (fp32) into the "out" region of d_out  (layout [b][c][n])
//   writes vT (bf16) into workspace                  (layout [b][n][c])
// ---------------------------------------------------------------------------
__global__ __launch_bounds__(256) void chan_softmax(const float* __restrict__ x,
                                                    float* __restrict__ xs,
                                                    __hip_bfloat16* __restrict__ vT)
{
    int idx = blockIdx.x * 256 + threadIdx.x;     // (b, n) flattened, 32768 total
    int b = idx >> 12;                            // / 4096
    int n = idx & (N_ - 1);

    const float* xp = x + (size_t)b * C_ * N_ + n;

    // online max + sum
    float m = -INFINITY, s = 0.f;
    #pragma unroll 8
    for (int c = 0; c < C_; ++c) {
        float v  = xp[(size_t)c * N_];
        float m2 = fmaxf(m, v);
        s = s * __expf(m - m2) + __expf(v - m2);
        m = m2;
    }
    float inv = 1.f / s;

    float* op = xs + (size_t)b * C_ * N_ + n;
    u16x8* vp = reinterpret_cast<u16x8*>(vT + ((size_t)b * N_ + n) * C_);

    for (int c0 = 0; c0 < C_; c0 += 8) {
        u16x8 pk;
        #pragma unroll
        for (int j = 0; j < 8; ++j) {
            float v = __expf(xp[(size_t)(c0 + j) * N_] - m) * inv;
            op[(size_t)(c0 + j) * N_] = v;
            __hip_bfloat16 hb = __float2bfloat16(v);
            pk[j] = *reinterpret_cast<unsigned short*>(&hb);
        }
        vp[c0 >> 3] = pk;   // 16B store, row-contiguous
    }
}

// ---------------------------------------------------------------------------
// Kernel B: energy[b][i][j] = sum_c vT[b][i][c] * vT[b][j][c]   (K = 128)
// 128x128 output tile per block (4 waves, 64x64 per wave, 16x16x32 bf16 MFMA).
// Fragments loaded directly from global (vT is 1MB/batch -> L2 resident).
// A and B fragments use the identical (group,slot)->k mapping, so the result
// is layout-permutation-invariant in k; C/D layout per verified m89 mapping.
// ---------------------------------------------------------------------------
__global__ __launch_bounds__(256) void energy_mfma(const __hip_bfloat16* __restrict__ vT,
                                                   float* __restrict__ att)
{
    int b  = blockIdx.z;
    int i0 = blockIdx.x * 128;
    int j0 = blockIdx.y * 128;

    int w    = threadIdx.x >> 6;
    int lane = threadIdx.x & 63;
    int wr = w >> 1, wc = w & 1;
    int r16 = lane & 15;          // row-in-16 for A / col for B and C
    int kg  = lane >> 4;          // k-group

    const __hip_bfloat16* base = vT + (size_t)b * N_ * C_;
    int arow0 = i0 + wr * 64 + r16;
    int brow0 = j0 + wc * 64 + r16;

    f32x4 acc[4][4] = {};

    #pragma unroll
    for (int ks = 0; ks < 4; ++ks) {
        int koff = ks * 32 + kg * 8;
        bf16x8 a[4], bb[4];
        #pragma unroll
        for (int mi = 0; mi < 4; ++mi)
            a[mi] = *reinterpret_cast<const bf16x8*>(base + (size_t)(arow0 + mi * 16) * C_ + koff);
        #pragma unroll
        for (int nj = 0; nj < 4; ++nj)
            bb[nj] = *reinterpret_cast<const bf16x8*>(base + (size_t)(brow0 + nj * 16) * C_ + koff);
        #pragma unroll
        for (int mi = 0; mi < 4; ++mi)
            #pragma unroll
            for (int nj = 0; nj < 4; ++nj)
                acc[mi][nj] = __builtin_amdgcn_mfma_f32_16x16x32_bf16(a[mi], bb[nj], acc[mi][nj], 0, 0, 0);
    }

    float* ab = att + (size_t)b * N_ * N_;
    #pragma unroll
    for (int mi = 0; mi < 4; ++mi) {
        int row = i0 + wr * 64 + mi * 16 + kg * 4;
        #pragma unroll
        for (int nj = 0; nj < 4; ++nj) {
            int col = j0 + wc * 64 + nj * 16 + r16;
            #pragma unroll
            for (int r = 0; r < 4; ++r)
                ab[(size_t)(row + r) * N_ + col] = acc[mi][nj][r];
        }
    }
}

// ---------------------------------------------------------------------------
// Kernel C: in-place row softmax over the last axis of att (rows of 4096).
// One 256-thread block per row; 16 values/thread held in registers.
// ---------------------------------------------------------------------------
__global__ __launch_bounds__(256) void row_softmax(float* __restrict__ att)
{
    size_t row = blockIdx.x;                       // b*N + n, 32768 rows
    float4* p = reinterpret_cast<float4*>(att + row * (size_t)N_);
    int t    = threadIdx.x;
    int lane = t & 63;
    int wid  = t >> 6;

    __shared__ float red[4];

    float4 v[4];
    float m = -INFINITY;
    #pragma unroll
    for (int i = 0; i < 4; ++i) {
        v[i] = p[t + 256 * i];
        m = fmaxf(m, fmaxf(fmaxf(v[i].x, v[i].y), fmaxf(v[i].z, v[i].w)));
    }
    #pragma unroll
    for (int off = 32; off; off >>= 1) m = fmaxf(m, __shfl_xor(m, off, 64));
    if (lane == 0) red[wid] = m;
    __syncthreads();
    m = fmaxf(fmaxf(red[0], red[1]), fmaxf(red[2], red[3]));
    __syncthreads();

    float e[16];
    float s = 0.f;
    #pragma unroll
    for (int i = 0; i < 4; ++i) {
        e[4*i+0] = __expf(v[i].x - m);
        e[4*i+1] = __expf(v[i].y - m);
        e[4*i+2] = __expf(v[i].z - m);
        e[4*i+3] = __expf(v[i].w - m);
        s += e[4*i+0] + e[4*i+1] + e[4*i+2] + e[4*i+3];
    }
    #pragma unroll
    for (int off = 32; off; off >>= 1) s += __shfl_xor(s, off, 64);
    if (lane == 0) red[wid] = s;
    __syncthreads();
    s = red[0] + red[1] + red[2] + red[3];
    float inv = 1.f / s;

    #pragma unroll
    for (int i = 0; i < 4; ++i) {
        float4 o;
        o.x = e[4*i+0] * inv; o.y = e[4*i+1] * inv;
        o.z = e[4*i+2] * inv; o.w = e[4*i+3] * inv;
        p[t + 256 * i] = o;
    }
}

// ---------------------------------------------------------------------------
// Kernel D: out = gamma * (V @ attention^T) + xs.
// The out region already holds xs; if gamma == 0 (the benchmark case) this is
// a no-op. The general path is a correct (if slow) fallback.
// ---------------------------------------------------------------------------
__global__ __launch_bounds__(128) void pv_update(const float* __restrict__ gamma,
                                                 const __hip_bfloat16* __restrict__ vT,
                                                 const float* __restrict__ att,
                                                 float* __restrict__ out)
{
    float g = gamma[0];
    if (g == 0.0f) return;

    int b = blockIdx.y;
    int n = blockIdx.x;
    int c = threadIdx.x;   // 128

    const float* arow = att + ((size_t)b * N_ + n) * N_;
    const __hip_bfloat16* vb = vT + (size_t)b * N_ * C_;

    float acc = 0.f;
    for (int m = 0; m < N_; ++m)
        acc += __bfloat162float(vb[(size_t)m * C_ + c]) * arow[m];

    size_t oi = ((size_t)b * C_ + c) * N_ + n;
    out[oi] = g * acc + out[oi];
}

// ---------------------------------------------------------------------------
extern "C" void kernel_launch(void* const* d_in, const int* in_sizes, int n_in,
                              void* d_out, int out_size, void* d_ws, size_t ws_size,
                              hipStream_t stream)
{
    const float* x     = (const float*)d_in[0];
    const float* gamma = (const float*)d_in[1];

    float* out = (float*)d_out;                       // [B][C][N]  (4,194,304 f32)
    float* att = out + (size_t)B_ * C_ * N_;          // [B][N][N]  (134,217,728 f32)
    __hip_bfloat16* vT = (__hip_bfloat16*)d_ws;       // [B][N][C]  bf16, 8 MB

    chan_softmax<<<(B_ * N_) / 256, 256, 0, stream>>>(x, out, vT);
    energy_mfma<<<dim3(N_ / 128, N_ / 128, B_), 256, 0, stream>>>(vT, att);
    row_softmax<<<B_ * N_, 256, 0, stream>>>(att);
    pv_update<<<dim3(N_, B_), C_, 0, stream>>>(gamma, vT, att, out);
}

// Round 2
// 215.865 us; speedup vs baseline: 1.8386x; 1.8386x over previous
//
#include <hip/hip_runtime.h>
#include <hip/hip_bf16.h>

#define B_ 8
#define C_ 128
#define N_ 4096   // H*W = 64*64

typedef __bf16 bf16x8 __attribute__((ext_vector_type(8)));
typedef float  f32x4  __attribute__((ext_vector_type(4)));
typedef unsigned short u16x8 __attribute__((ext_vector_type(8)));

// ---------------------------------------------------------------------------
// Kernel A: channel softmax over C for each (b, n).
//   writes xs (fp32) into the "out" region of d_out  (layout [b][c][n])
//   writes vT (bf16) into workspace                  (layout [b][n][c])
// ---------------------------------------------------------------------------
__global__ __launch_bounds__(256) void chan_softmax(const float* __restrict__ x,
                                                    float* __restrict__ xs,
                                                    __hip_bfloat16* __restrict__ vT)
{
    int idx = blockIdx.x * 256 + threadIdx.x;     // (b, n) flattened, 32768 total
    int b = idx >> 12;                            // / 4096
    int n = idx & (N_ - 1);

    const float* xp = x + (size_t)b * C_ * N_ + n;

    // online max + sum
    float m = -INFINITY, s = 0.f;
    #pragma unroll 8
    for (int c = 0; c < C_; ++c) {
        float v  = xp[(size_t)c * N_];
        float m2 = fmaxf(m, v);
        s = s * __expf(m - m2) + __expf(v - m2);
        m = m2;
    }
    float inv = 1.f / s;

    float* op = xs + (size_t)b * C_ * N_ + n;
    u16x8* vp = reinterpret_cast<u16x8*>(vT + ((size_t)b * N_ + n) * C_);

    for (int c0 = 0; c0 < C_; c0 += 8) {
        u16x8 pk;
        #pragma unroll
        for (int j = 0; j < 8; ++j) {
            float v = __expf(xp[(size_t)(c0 + j) * N_] - m) * inv;
            op[(size_t)(c0 + j) * N_] = v;
            __hip_bfloat16 hb = __float2bfloat16(v);
            pk[j] = *reinterpret_cast<unsigned short*>(&hb);
        }
        vp[c0 >> 3] = pk;   // 16B store, row-contiguous
    }
}

// ---------------------------------------------------------------------------
// Kernel B (fused): attention[b][i][j] = softmax_j( vT[b][i][:] . vT[b][j][:] )
//
// Each block owns a 64-row x 4096-col stripe. Since e = <v_i, v_j> in [0,1]
// (dot of probability vectors), softmax needs NO max subtraction:
//   att = exp(e) / sum_j exp(e),   exp(e) <= e^1, sum >= 4096.
// Pass 1: MFMA energy tiles, accumulate per-row sum of exp (nothing written).
// Pass 2: recompute tiles (K=128 -> recompute is ~17us chip-wide, vs 1.07 GB
// of HBM for a separate softmax pass), write exp(e)*inv directly.
//
// A fragments (64 rows x 128 K) live in registers across both passes.
// blockIdx%8 = batch so each XCD's round-robin share stays on one batch's
// 1 MB vT panel (L2-resident).
// ---------------------------------------------------------------------------
__global__ __launch_bounds__(256, 2) void energy_softmax_fused(
    const __hip_bfloat16* __restrict__ vT, float* __restrict__ att)
{
    int bid = blockIdx.x;
    int b = bid & 7;                       // batch pinned to XCD
    int rowbase = (bid >> 3) * 64;

    int w    = threadIdx.x >> 6;           // wave id: column window within tile
    int lane = threadIdx.x & 63;
    int r16  = lane & 15;
    int kg   = lane >> 4;

    const __hip_bfloat16* base = vT + (size_t)b * N_ * C_;

    // A fragments: rows rowbase..rowbase+63, full K=128. 16 x bf16x8 = 64 VGPR.
    bf16x8 a[4][4];
    #pragma unroll
    for (int mi = 0; mi < 4; ++mi)
        #pragma unroll
        for (int ks = 0; ks < 4; ++ks)
            a[mi][ks] = *reinterpret_cast<const bf16x8*>(
                base + (size_t)(rowbase + mi * 16 + r16) * C_ + ks * 32 + kg * 8);

    __shared__ float smem[4][64];

    float rsum[4][4] = {};

    // ---------------- Pass 1: row sums of exp(e) ----------------
    #pragma unroll 1
    for (int jt = 0; jt < 16; ++jt) {
        int colbase = jt * 256 + w * 64;
        f32x4 acc[4][4] = {};
        #pragma unroll
        for (int ks = 0; ks < 4; ++ks) {
            bf16x8 bb[4];
            #pragma unroll
            for (int nj = 0; nj < 4; ++nj)
                bb[nj] = *reinterpret_cast<const bf16x8*>(
                    base + (size_t)(colbase + nj * 16 + r16) * C_ + ks * 32 + kg * 8);
            #pragma unroll
            for (int mi = 0; mi < 4; ++mi)
                #pragma unroll
                for (int nj = 0; nj < 4; ++nj)
                    acc[mi][nj] = __builtin_amdgcn_mfma_f32_16x16x32_bf16(
                        a[mi][ks], bb[nj], acc[mi][nj], 0, 0, 0);
        }
        #pragma unroll
        for (int mi = 0; mi < 4; ++mi)
            #pragma unroll
            for (int r = 0; r < 4; ++r) {
                float s = 0.f;
                #pragma unroll
                for (int nj = 0; nj < 4; ++nj) s += __expf(acc[mi][nj][r]);
                rsum[mi][r] += s;
            }
    }

    // reduce over the 16 lanes (r16) holding this row's column slices
    #pragma unroll
    for (int off = 1; off < 16; off <<= 1)
        #pragma unroll
        for (int mi = 0; mi < 4; ++mi)
            #pragma unroll
            for (int r = 0; r < 4; ++r)
                rsum[mi][r] += __shfl_xor(rsum[mi][r], off, 64);

    if (r16 == 0) {
        #pragma unroll
        for (int mi = 0; mi < 4; ++mi)
            #pragma unroll
            for (int r = 0; r < 4; ++r)
                smem[w][mi * 16 + kg * 4 + r] = rsum[mi][r];
    }
    __syncthreads();

    float inv[4][4];
    #pragma unroll
    for (int mi = 0; mi < 4; ++mi)
        #pragma unroll
        for (int r = 0; r < 4; ++r) {
            int row = mi * 16 + kg * 4 + r;
            inv[mi][r] = 1.f / (smem[0][row] + smem[1][row] + smem[2][row] + smem[3][row]);
        }

    float* ab = att + (size_t)b * N_ * N_;

    // ---------------- Pass 2: recompute, write softmaxed ----------------
    #pragma unroll 1
    for (int jt = 0; jt < 16; ++jt) {
        int colbase = jt * 256 + w * 64;
        f32x4 acc[4][4] = {};
        #pragma unroll
        for (int ks = 0; ks < 4; ++ks) {
            bf16x8 bb[4];
            #pragma unroll
            for (int nj = 0; nj < 4; ++nj)
                bb[nj] = *reinterpret_cast<const bf16x8*>(
                    base + (size_t)(colbase + nj * 16 + r16) * C_ + ks * 32 + kg * 8);
            #pragma unroll
            for (int mi = 0; mi < 4; ++mi)
                #pragma unroll
                for (int nj = 0; nj < 4; ++nj)
                    acc[mi][nj] = __builtin_amdgcn_mfma_f32_16x16x32_bf16(
                        a[mi][ks], bb[nj], acc[mi][nj], 0, 0, 0);
        }
        #pragma unroll
        for (int mi = 0; mi < 4; ++mi) {
            int row = rowbase + mi * 16 + kg * 4;
            #pragma unroll
            for (int nj = 0; nj < 4; ++nj) {
                int col = colbase + nj * 16 + r16;
                #pragma unroll
                for (int r = 0; r < 4; ++r)
                    ab[(size_t)(row + r) * N_ + col] = __expf(acc[mi][nj][r]) * inv[mi][r];
            }
        }
    }
}

// ---------------------------------------------------------------------------
// Kernel D: out = gamma * (V @ attention^T) + xs.
// The out region already holds xs; if gamma == 0 (the benchmark case) this is
// a no-op. The general path is a correct (if slow) fallback.
// ---------------------------------------------------------------------------
__global__ __launch_bounds__(128) void pv_update(const float* __restrict__ gamma,
                                                 const __hip_bfloat16* __restrict__ vT,
                                                 const float* __restrict__ att,
                                                 float* __restrict__ out)
{
    float g = gamma[0];
    if (g == 0.0f) return;

    int b = blockIdx.y;
    int n = blockIdx.x;
    int c = threadIdx.x;   // 128

    const float* arow = att + ((size_t)b * N_ + n) * N_;
    const __hip_bfloat16* vb = vT + (size_t)b * N_ * C_;

    float acc = 0.f;
    for (int m = 0; m < N_; ++m)
        acc += __bfloat162float(vb[(size_t)m * C_ + c]) * arow[m];

    size_t oi = ((size_t)b * C_ + c) * N_ + n;
    out[oi] = g * acc + out[oi];
}

// ---------------------------------------------------------------------------
extern "C" void kernel_launch(void* const* d_in, const int* in_sizes, int n_in,
                              void* d_out, int out_size, void* d_ws, size_t ws_size,
                              hipStream_t stream)
{
    const float* x     = (const float*)d_in[0];
    const float* gamma = (const float*)d_in[1];

    float* out = (float*)d_out;                       // [B][C][N]  (4,194,304 f32)
    float* att = out + (size_t)B_ * C_ * N_;          // [B][N][N]  (134,217,728 f32)
    __hip_bfloat16* vT = (__hip_bfloat16*)d_ws;       // [B][N][C]  bf16, 8 MB

    chan_softmax<<<(B_ * N_) / 256, 256, 0, stream>>>(x, out, vT);
    energy_softmax_fused<<<(N_ / 64) * B_, 256, 0, stream>>>(vT, att);
    pv_update<<<dim3(N_, B_), C_, 0, stream>>>(gamma, vT, att, out);
}